// Round 1
// baseline (11.291 us; speedup 1.0000x reference)
//
#include <hip/hip_runtime.h>

#define NCOLS 1024
#define NROWS 32

__global__ __launch_bounds__(256) void bpmll_row_kernel(
    const float* __restrict__ c, const int* __restrict__ y,
    float* __restrict__ ws) {
    const int row = blockIdx.x;
    const int tid = threadIdx.x;
    // c row is [c1_0, s1_0, c1_1, s1_1, ...] -> float2 stream
    const float2* __restrict__ crow =
        reinterpret_cast<const float2*>(c + (size_t)row * 2 * NCOLS);
    const int* __restrict__ yrow = y + (size_t)row * NCOLS;

    float sy = 0.f, sA = 0.f, sB = 0.f, sC = 0.f, sD = 0.f;
    #pragma unroll
    for (int k = 0; k < NCOLS / 256; ++k) {
        const int col = k * 256 + tid;
        const float2 cs = crow[col];         // cs.x = c1, cs.y = s1
        const float yf = (float)yrow[col];
        const float yb = 1.f - yf;
        const float ec  = __expf(cs.x);      // exp(c1)
        const float enc = __expf(-cs.x);     // exp(-c1)
        const float es  = __expf(cs.y);      // exp(s1)
        const float ens = __expf(-cs.y);     // exp(-s1)
        sy += yf;
        sA += yf * enc;
        sC += yb * ec;
        sB += yb * ens;
        sD += yf * es;
    }
    // wave (64-lane) butterfly reduce
    #pragma unroll
    for (int off = 32; off > 0; off >>= 1) {
        sy += __shfl_down(sy, off);
        sA += __shfl_down(sA, off);
        sB += __shfl_down(sB, off);
        sC += __shfl_down(sC, off);
        sD += __shfl_down(sD, off);
    }
    __shared__ float red[4][5];
    const int wave = tid >> 6;
    const int lane = tid & 63;
    if (lane == 0) {
        red[wave][0] = sy; red[wave][1] = sA; red[wave][2] = sB;
        red[wave][3] = sC; red[wave][4] = sD;
    }
    __syncthreads();
    if (tid == 0) {
        float ty = 0.f, tA = 0.f, tB = 0.f, tC = 0.f, tD = 0.f;
        #pragma unroll
        for (int w = 0; w < 4; ++w) {
            ty += red[w][0]; tA += red[w][1]; tB += red[w][2];
            tC += red[w][3]; tD += red[w][4];
        }
        const float yn  = ty;
        const float ybn = (float)NCOLS - ty;
        const float denom = 2.f * yn * ybn + yn * yn + ybn * ybn;
        ws[row] = (tA + tB) * (tC + tD) / denom;
    }
}

__global__ __launch_bounds__(64) void bpmll_final_kernel(
    const float* __restrict__ ws, float* __restrict__ out) {
    const int lane = threadIdx.x;
    float v = (lane < NROWS) ? ws[lane] : 0.f;
    #pragma unroll
    for (int off = 32; off > 0; off >>= 1) v += __shfl_down(v, off);
    if (lane == 0) out[0] = v * (1.f / NROWS);
}

extern "C" void kernel_launch(void* const* d_in, const int* in_sizes, int n_in,
                              void* d_out, int out_size, void* d_ws, size_t ws_size,
                              hipStream_t stream) {
    const float* c = (const float*)d_in[0];
    const int*   y = (const int*)d_in[1];
    float* out = (float*)d_out;
    float* ws  = (float*)d_ws;
    bpmll_row_kernel<<<NROWS, 256, 0, stream>>>(c, y, ws);
    bpmll_final_kernel<<<1, 64, 0, stream>>>(ws, out);
}